// Round 10
// baseline (148.354 us; speedup 1.0000x reference)
//
#include <hip/hip_runtime.h>
#include <hip/hip_fp16.h>

#define D 96
#define D4 24
#define MAXBINS 256   // buckets of 256 nodes; n <= 65536

static inline size_t alignup(size_t x) { return (x + 255) & ~size_t(255); }

__device__ inline float4 f4fma(float s, float4 a, float4 acc) {
    acc.x = fmaf(s, a.x, acc.x);
    acc.y = fmaf(s, a.y, acc.y);
    acc.z = fmaf(s, a.z, acc.z);
    acc.w = fmaf(s, a.w, acc.w);
    return acc;
}

// unpack 8 fp16 (uint4) and FMA into two float4 accumulators
__device__ inline void u4fma(uint4 rv, float w, float4& a0, float4& a1) {
    __half2 h0 = *reinterpret_cast<__half2*>(&rv.x);
    __half2 h1 = *reinterpret_cast<__half2*>(&rv.y);
    __half2 h2 = *reinterpret_cast<__half2*>(&rv.z);
    __half2 h3 = *reinterpret_cast<__half2*>(&rv.w);
    float2 f0 = __half22float2(h0);
    float2 f1 = __half22float2(h1);
    float2 f2 = __half22float2(h2);
    float2 f3 = __half22float2(h3);
    a0.x = fmaf(w, f0.x, a0.x);
    a0.y = fmaf(w, f0.y, a0.y);
    a0.z = fmaf(w, f1.x, a0.z);
    a0.w = fmaf(w, f1.y, a0.w);
    a1.x = fmaf(w, f2.x, a1.x);
    a1.y = fmaf(w, f2.y, a1.y);
    a1.z = fmaf(w, f3.x, a1.z);
    a1.w = fmaf(w, f3.y, a1.w);
}

// ---- bucket-sort pipeline (no per-edge global atomics) ----

// Per-block LDS histogram of dst>>8; bhist is block-major [b*nbins + bin] (coalesced).
__global__ __launch_bounds__(1024) void hist_kernel(const int* __restrict__ dst, int E,
                                                    int* __restrict__ bhist, int nbins) {
    __shared__ int h[MAXBINS];
    const int tid = threadIdx.x;
    if (tid < nbins) h[tid] = 0;
    __syncthreads();
    int e = blockIdx.x * 1024 + tid;
    if (e < E) atomicAdd(&h[dst[e] >> 8], 1);
    __syncthreads();
    if (tid < nbins) bhist[blockIdx.x * nbins + tid] = h[tid];
}

// Hierarchical exclusive scan, phase 1, over bhist PERMUTED to bin-major order:
// scan index i <-> (bin = i/nblk, b = i%nblk). Local result; bsum per scan-block.
__global__ __launch_bounds__(1024) void scan1_kernel(const int* __restrict__ bhist,
                                                     int* __restrict__ boffs,
                                                     int* __restrict__ bsum,
                                                     int m, int nblk, int nbins) {
    __shared__ int wsum[16];
    const int i = blockIdx.x * 1024 + threadIdx.x;
    const int lane = threadIdx.x & 63;
    const int wid  = threadIdx.x >> 6;
    int v = 0;
    if (i < m) {
        int b = i % nblk, bin = i / nblk;
        v = bhist[b * nbins + bin];
    }
    int sc = v;
    #pragma unroll
    for (int off = 1; off < 64; off <<= 1) {
        int t = __shfl_up(sc, off);
        if (lane >= off) sc += t;
    }
    if (lane == 63) wsum[wid] = sc;
    __syncthreads();
    int wprefix = 0;
    #pragma unroll
    for (int k = 0; k < 16; ++k)
        if (k < wid) wprefix += wsum[k];
    if (i < m) boffs[i] = wprefix + (sc - v);
    if (threadIdx.x == 1023) bsum[blockIdx.x] = wprefix + sc;
}

// Phase 2: one block scans scan-block sums (nb <= 1024) -> bboff.
__global__ __launch_bounds__(1024) void scan2_kernel(const int* __restrict__ bsum,
                                                     int* __restrict__ boff, int nb) {
    __shared__ int wsum[16];
    const int lane = threadIdx.x & 63;
    const int wid  = threadIdx.x >> 6;
    int v = ((int)threadIdx.x < nb) ? bsum[threadIdx.x] : 0;
    int sc = v;
    #pragma unroll
    for (int off = 1; off < 64; off <<= 1) {
        int t = __shfl_up(sc, off);
        if (lane >= off) sc += t;
    }
    if (lane == 63) wsum[wid] = sc;
    __syncthreads();
    int wprefix = 0;
    #pragma unroll
    for (int k = 0; k < 16; ++k)
        if (k < wid) wprefix += wsum[k];
    if ((int)threadIdx.x < nb) boff[threadIdx.x] = wprefix + (sc - v);
}

// Distribute edges grouped by bucket (LDS ranking only, contiguous chunk writes).
// Consumes LOCAL boffs + bboff (scan3 folded in here).
__global__ __launch_bounds__(1024) void dist_kernel(const int* __restrict__ src,
                                                    const int* __restrict__ dst, int E,
                                                    const int* __restrict__ boffs,
                                                    const int* __restrict__ bboff,
                                                    int nblk, int nbins,
                                                    int2* __restrict__ ebuf) {
    __shared__ int h[MAXBINS];
    __shared__ int base[MAXBINS];
    const int tid = threadIdx.x;
    if (tid < nbins) h[tid] = 0;
    __syncthreads();
    int e = blockIdx.x * 1024 + tid;
    int s = 0, d = 0, bin = 0, rank = 0;
    bool valid = e < E;
    if (valid) {
        s = src[e]; d = dst[e];
        bin = d >> 8;
        rank = atomicAdd(&h[bin], 1);
    }
    __syncthreads();
    if (tid < nbins) {
        int idx = tid * nblk + blockIdx.x;
        base[tid] = boffs[idx] + bboff[idx >> 10];
    }
    __syncthreads();
    if (valid) ebuf[base[bin] + rank] = make_int2(s, d);
}

// One workgroup per bucket (256 nodes): count low-8 dst in LDS, prefix-scan,
// write dinv + rowptr (bucket base + local prefix).
// MUST be a separate launch from bucketB: bucketB reads dinv of arbitrary
// (other-bucket) src nodes, so all dinv writes must complete first.
__global__ __launch_bounds__(256) void bucketA_kernel(const int2* __restrict__ ebuf,
                                                      const int* __restrict__ boffs,
                                                      const int* __restrict__ bboff,
                                                      int nblk, int nbins,
                                                      float* __restrict__ dinv,
                                                      int* __restrict__ rowptr,
                                                      int n, int E) {
    __shared__ int cnt[256];
    __shared__ int wsum[4];
    const int k = blockIdx.x;
    const int tid = threadIdx.x;
    int i0 = k * nblk, i1 = (k + 1) * nblk;
    const int bstart = boffs[i0] + bboff[i0 >> 10];
    const int bend = (k + 1 < nbins) ? (boffs[i1] + bboff[i1 >> 10]) : E;
    cnt[tid] = 0;
    __syncthreads();
    for (int e = bstart + tid; e < bend; e += 256)
        atomicAdd(&cnt[ebuf[e].y & 255], 1);
    __syncthreads();
    int v = cnt[tid];
    const int lane = tid & 63, wid = tid >> 6;
    int sc = v;
    #pragma unroll
    for (int off = 1; off < 64; off <<= 1) {
        int t = __shfl_up(sc, off);
        if (lane >= off) sc += t;
    }
    if (lane == 63) wsum[wid] = sc;
    __syncthreads();
    int wprefix = 0;
    #pragma unroll
    for (int w = 0; w < 4; ++w)
        if (w < wid) wprefix += wsum[w];
    int node = k * 256 + tid;
    if (node < n) {
        dinv[node] = rsqrtf((float)(v + 1));      // +1 = self-loop
        rowptr[node] = bstart + wprefix + (sc - v);
    }
    if (k == nbins - 1 && tid == 0) rowptr[n] = E;
}

// Fill CSR: cursors seeded from rowptr; all writes land in this bucket's
// contiguous region -> full-line writebacks. dinv is globally complete here.
__global__ __launch_bounds__(256) void bucketB_kernel(const int2* __restrict__ ebuf,
                                                      const int* __restrict__ boffs,
                                                      const int* __restrict__ bboff,
                                                      int nblk, int nbins,
                                                      const int* __restrict__ rowptr,
                                                      const float* __restrict__ dinv,
                                                      int2* __restrict__ csr, int n, int E) {
    __shared__ int cur[256];
    const int k = blockIdx.x;
    const int tid = threadIdx.x;
    int i0 = k * nblk, i1 = (k + 1) * nblk;
    const int bstart = boffs[i0] + bboff[i0 >> 10];
    const int bend = (k + 1 < nbins) ? (boffs[i1] + bboff[i1 >> 10]) : E;
    int node = k * 256 + tid;
    cur[tid] = (node < n) ? rowptr[node] : 0;
    __syncthreads();
    for (int e = bstart + tid; e < bend; e += 256) {
        int2 ed = ebuf[e];
        int pos = atomicAdd(&cur[ed.y & 255], 1);
        csr[pos] = make_int2(ed.x, __float_as_int(dinv[ed.x]));
    }
}

// ---- dense transform + aggregation ----

// Y[n,96](fp16) = X[n,96](fp32) @ W[96,96](fp32).
__global__ __launch_bounds__(192) void matmul_kernel(const float* __restrict__ X,
                                                     const float* __restrict__ W,
                                                     uint2* __restrict__ Y, int n) {
    __shared__ float XsT[96 * 64];
    const int t = threadIdx.x;        // 0..23 col-group
    const int y = threadIdx.y;        // 0..7 row-group
    const int tid = y * 24 + t;
    const int row0 = blockIdx.x * 64;
    const float4* X4 = (const float4*)X;

    for (int i = tid; i < 64 * 24; i += 192) {
        int r = i / 24, c4 = i % 24;
        float4 v = make_float4(0.f, 0.f, 0.f, 0.f);
        if (row0 + r < n) v = X4[(size_t)(row0 + r) * D4 + c4];
        int rs = r ^ ((c4 & 15) << 2);
        XsT[(c4 * 4 + 0) * 64 + rs] = v.x;
        XsT[(c4 * 4 + 1) * 64 + rs] = v.y;
        XsT[(c4 * 4 + 2) * 64 + rs] = v.z;
        XsT[(c4 * 4 + 3) * 64 + rs] = v.w;
    }
    __syncthreads();

    const float4* W4 = (const float4*)W;
    float4 acc[8];
    #pragma unroll
    for (int r = 0; r < 8; ++r) acc[r] = make_float4(0.f, 0.f, 0.f, 0.f);
    const int rbase = y * 8;

    #pragma unroll 8
    for (int k = 0; k < 96; ++k) {
        float4 w = W4[k * D4 + t];
        int base0 = (rbase ^ (((k >> 2) & 15) << 2));
        float4 xa = *(const float4*)&XsT[k * 64 + base0];
        float4 xb = *(const float4*)&XsT[k * 64 + (base0 ^ 4)];
        acc[0] = f4fma(xa.x, w, acc[0]);
        acc[1] = f4fma(xa.y, w, acc[1]);
        acc[2] = f4fma(xa.z, w, acc[2]);
        acc[3] = f4fma(xa.w, w, acc[3]);
        acc[4] = f4fma(xb.x, w, acc[4]);
        acc[5] = f4fma(xb.y, w, acc[5]);
        acc[6] = f4fma(xb.z, w, acc[6]);
        acc[7] = f4fma(xb.w, w, acc[7]);
    }

    #pragma unroll
    for (int r = 0; r < 8; ++r) {
        int row = row0 + rbase + r;
        if (row < n) {
            __half2 ha = __float22half2_rn(make_float2(acc[r].x, acc[r].y));
            __half2 hb = __float22half2_rn(make_float2(acc[r].z, acc[r].w));
            uint2 st;
            st.x = *reinterpret_cast<unsigned int*>(&ha);
            st.y = *reinterpret_cast<unsigned int*>(&hb);
            Y[(size_t)row * D4 + t] = st;
        }
    }
}

// out[i,:] = prelu( dinv[i]*sum_e w_e*XW[src_e,:] + dinv[i]^2*XW[i,:] + b ), XW fp16.
// block (12,32): 12 lanes/node x 16B uint4 (128B in flight per lane at x8 unroll).
__global__ __launch_bounds__(384) void aggregate_kernel(const uint4* __restrict__ XH4,
                                                        const int2* __restrict__ csr,
                                                        const int* __restrict__ rowptr,
                                                        const float* __restrict__ dinv,
                                                        const float4* __restrict__ b4,
                                                        const float4* __restrict__ pa4,
                                                        float4* __restrict__ out4, int n) {
    const int i = blockIdx.x * 32 + threadIdx.y;
    const int t = threadIdx.x;  // 0..11
    if (i >= n) return;
    const int beg = rowptr[i], end = rowptr[i + 1];
    float4 a0 = make_float4(0.f, 0.f, 0.f, 0.f);
    float4 a1 = make_float4(0.f, 0.f, 0.f, 0.f);
    int p = beg;
    for (; p + 8 <= end; p += 8) {
        int2 e0 = csr[p + 0];
        int2 e1 = csr[p + 1];
        int2 e2 = csr[p + 2];
        int2 e3 = csr[p + 3];
        int2 e4 = csr[p + 4];
        int2 e5 = csr[p + 5];
        int2 e6 = csr[p + 6];
        int2 e7 = csr[p + 7];
        uint4 r0 = XH4[(size_t)e0.x * 12 + t];
        uint4 r1 = XH4[(size_t)e1.x * 12 + t];
        uint4 r2 = XH4[(size_t)e2.x * 12 + t];
        uint4 r3 = XH4[(size_t)e3.x * 12 + t];
        uint4 r4 = XH4[(size_t)e4.x * 12 + t];
        uint4 r5 = XH4[(size_t)e5.x * 12 + t];
        uint4 r6 = XH4[(size_t)e6.x * 12 + t];
        uint4 r7 = XH4[(size_t)e7.x * 12 + t];
        u4fma(r0, __int_as_float(e0.y), a0, a1);
        u4fma(r1, __int_as_float(e1.y), a0, a1);
        u4fma(r2, __int_as_float(e2.y), a0, a1);
        u4fma(r3, __int_as_float(e3.y), a0, a1);
        u4fma(r4, __int_as_float(e4.y), a0, a1);
        u4fma(r5, __int_as_float(e5.y), a0, a1);
        u4fma(r6, __int_as_float(e6.y), a0, a1);
        u4fma(r7, __int_as_float(e7.y), a0, a1);
    }
    if (p + 4 <= end) {
        int2 e0 = csr[p + 0];
        int2 e1 = csr[p + 1];
        int2 e2 = csr[p + 2];
        int2 e3 = csr[p + 3];
        uint4 r0 = XH4[(size_t)e0.x * 12 + t];
        uint4 r1 = XH4[(size_t)e1.x * 12 + t];
        uint4 r2 = XH4[(size_t)e2.x * 12 + t];
        uint4 r3 = XH4[(size_t)e3.x * 12 + t];
        u4fma(r0, __int_as_float(e0.y), a0, a1);
        u4fma(r1, __int_as_float(e1.y), a0, a1);
        u4fma(r2, __int_as_float(e2.y), a0, a1);
        u4fma(r3, __int_as_float(e3.y), a0, a1);
        p += 4;
    }
    for (; p < end; ++p) {
        int2 e = csr[p];
        u4fma(XH4[(size_t)e.x * 12 + t], __int_as_float(e.y), a0, a1);
    }
    const float di = dinv[i];
    float4 s0 = make_float4(0.f, 0.f, 0.f, 0.f);
    float4 s1 = make_float4(0.f, 0.f, 0.f, 0.f);
    u4fma(XH4[(size_t)i * 12 + t], 1.f, s0, s1);
    float4 b0 = b4[2 * t], b1 = b4[2 * t + 1];
    float4 q0 = pa4[2 * t], q1 = pa4[2 * t + 1];
    float4 v0, v1;
    v0.x = fmaf(di, a0.x, di * di * s0.x) + b0.x;
    v0.y = fmaf(di, a0.y, di * di * s0.y) + b0.y;
    v0.z = fmaf(di, a0.z, di * di * s0.z) + b0.z;
    v0.w = fmaf(di, a0.w, di * di * s0.w) + b0.w;
    v1.x = fmaf(di, a1.x, di * di * s1.x) + b1.x;
    v1.y = fmaf(di, a1.y, di * di * s1.y) + b1.y;
    v1.z = fmaf(di, a1.z, di * di * s1.z) + b1.z;
    v1.w = fmaf(di, a1.w, di * di * s1.w) + b1.w;
    v0.x = v0.x > 0.f ? v0.x : q0.x * v0.x;
    v0.y = v0.y > 0.f ? v0.y : q0.y * v0.y;
    v0.z = v0.z > 0.f ? v0.z : q0.z * v0.z;
    v0.w = v0.w > 0.f ? v0.w : q0.w * v0.w;
    v1.x = v1.x > 0.f ? v1.x : q1.x * v1.x;
    v1.y = v1.y > 0.f ? v1.y : q1.y * v1.y;
    v1.z = v1.z > 0.f ? v1.z : q1.z * v1.z;
    v1.w = v1.w > 0.f ? v1.w : q1.w * v1.w;
    out4[(size_t)i * D4 + 2 * t] = v0;
    out4[(size_t)i * D4 + 2 * t + 1] = v1;
}

extern "C" void kernel_launch(void* const* d_in, const int* in_sizes, int n_in,
                              void* d_out, int out_size, void* d_ws, size_t ws_size,
                              hipStream_t stream) {
    const float* x   = (const float*)d_in[0];
    const int*   ei  = (const int*)d_in[1];
    const float* W1  = (const float*)d_in[2];
    const float* b1  = (const float*)d_in[3];
    const float* W2  = (const float*)d_in[4];
    const float* b2  = (const float*)d_in[5];
    const float* pa  = (const float*)d_in[6];
    const int n = in_sizes[0] / D;
    const int E = in_sizes[1] / 2;
    const int* srcp = ei;
    const int* dstp = ei + E;

    const int nbins  = (n + 255) / 256;
    const int nblk_e = (E + 1023) / 1024;
    const int m      = nbins * nblk_e;
    const int nbscan = (m + 1023) / 1024;

    char* w = (char*)d_ws;
    int*   bhist  = (int*)w;   w += alignup((size_t)m * 4);
    int*   boffs  = (int*)w;   w += alignup((size_t)m * 4);
    int*   bsum   = (int*)w;   w += alignup(1024 * 4);
    int*   bboff  = (int*)w;   w += alignup(1024 * 4);
    float* dinv   = (float*)w; w += alignup((size_t)n * 4);
    int*   rowptr = (int*)w;   w += alignup((size_t)(n + 1) * 4);
    int2*  ebuf   = (int2*)w;  w += alignup((size_t)E * 8);
    int2*  csr    = (int2*)w;  w += alignup((size_t)E * 8);
    uint4* xw     = (uint4*)w; w += alignup((size_t)n * D * 2);  // fp16 rows
    float* out    = (float*)d_out;

    hist_kernel<<<nblk_e, 1024, 0, stream>>>(dstp, E, bhist, nbins);
    scan1_kernel<<<nbscan, 1024, 0, stream>>>(bhist, boffs, bsum, m, nblk_e, nbins);
    scan2_kernel<<<1, 1024, 0, stream>>>(bsum, bboff, nbscan);
    dist_kernel<<<nblk_e, 1024, 0, stream>>>(srcp, dstp, E, boffs, bboff, nblk_e, nbins, ebuf);
    bucketA_kernel<<<nbins, 256, 0, stream>>>(ebuf, boffs, bboff, nblk_e, nbins,
                                              dinv, rowptr, n, E);
    bucketB_kernel<<<nbins, 256, 0, stream>>>(ebuf, boffs, bboff, nblk_e, nbins,
                                              rowptr, dinv, csr, n, E);

    dim3 mblk(24, 8);
    const int mgrid = (n + 63) / 64;
    dim3 ablk(12, 32);
    const int agrid = (n + 31) / 32;

    matmul_kernel<<<mgrid, mblk, 0, stream>>>(x, W1, (uint2*)xw, n);
    aggregate_kernel<<<agrid, ablk, 0, stream>>>(xw, csr, rowptr, dinv,
                                                 (const float4*)b1, (const float4*)pa, (float4*)out, n);
    matmul_kernel<<<mgrid, mblk, 0, stream>>>(out, W2, (uint2*)xw, n);
    aggregate_kernel<<<agrid, ablk, 0, stream>>>(xw, csr, rowptr, dinv,
                                                 (const float4*)b2, (const float4*)pa, (float4*)out, n);
}